// Round 9
// baseline (294.739 us; speedup 1.0000x reference)
//
#include <hip/hip_runtime.h>
#include <stdint.h>

// sign-binarized 3x3 conv via XNOR-popcount.
// N=32, Cin=Cout=256, H=W=56, K=3, pad=1, stride=1.
//
// ws layout:
//   xb   : packed activations with zero halo, [N][58][58][8] u32  (channel-packed)
//   wb   : packed weights [Cout][9 taps][4] u64  (= [Cout][72] u32)
//   wcorr: per-(edge-pattern, co) popcount correction, [9][COUT] u32

#define CIN  256
#define COUT 256
#define HH   56
#define WW   56
#define NN   32
#define HP   58                 // 56 + 2 halo
#define HWI  (HH*WW)            // 3136
#define CO_CHUNK 32             // co per block in conv (grid.y = COUT/CO_CHUNK)

typedef unsigned long long u64;
typedef unsigned int u32;

#define XB_BYTES ((size_t)NN*HP*HP*8*4)          // 3,444,736
#define WB_BYTES ((size_t)COUT*9*4*8)            // 73,728
#define WC_BYTES ((size_t)9*COUT*4)              // 9,216

// ---------------- Pass 0: pack weights + edge-pattern corrections ----------
__global__ __launch_bounds__(256) void pack_w_kernel(const float* __restrict__ M,
                                                     u64* __restrict__ wb,
                                                     u32* __restrict__ wcorr) {
    int co   = blockIdx.x;
    int lane = threadIdx.x & 63;
    int cg   = threadIdx.x >> 6;          // channel group 0..3 (one per wave)
    __shared__ u32 pp[9 * 4];
    __shared__ u32 wp[9];

    int c = cg * 64 + lane;
    const float* Mb = M + ((size_t)co * CIN + c) * 9;   // OIHW, 9 taps contiguous
    #pragma unroll
    for (int t = 0; t < 9; ++t) {
        float v = Mb[t];
        u64 b = __ballot(v >= 0.0f);      // bit lane = sign bit of channel c
        if (lane == 0) {
            wb[((size_t)co * 9 + t) * 4 + cg] = b;
            pp[t * 4 + cg] = (u32)__popcll(b);
        }
    }
    __syncthreads();
    if (threadIdx.x < 9) {
        int t = threadIdx.x;
        wp[t] = pp[t*4+0] + pp[t*4+1] + pp[t*4+2] + pp[t*4+3];
    }
    __syncthreads();
    if (threadIdx.x < 9) {
        // edge pattern pid = hs*3+ws; hs/ws: 0=low edge,1=interior,2=high edge
        int pid = threadIdx.x;
        int hs = pid / 3, ws = pid % 3;
        u32 corr = 0;
        #pragma unroll
        for (int t = 0; t < 9; ++t) {
            int dh = t / 3 - 1, dw = t % 3 - 1;
            bool inval = (hs == 0 && dh == -1) || (hs == 2 && dh == 1) ||
                         (ws == 0 && dw == -1) || (ws == 2 && dw == 1);
            if (inval) corr += wp[t];
        }
        wcorr[pid * COUT + co] = corr;    // [pid][co] so conv reads with imm offset
    }
}

// ---------------- Pass 1: binarize x, channel-pack via ballot transpose ----
// Grid (N*58, 2); 4 waves/block, each wave owns 32 channels (u32 slot).
// Halo rows/cols written as zeros here -> no separate memset dispatch.
// Serial ballot chain per wave halved vs round 6 (32 not 64); 14.5 waves/SIMD.
__global__ __launch_bounds__(256) void pack_x_kernel(const float* __restrict__ x,
                                                     u32* __restrict__ xb) {
    int bx   = blockIdx.x;                // n*58 + hp
    int n    = bx / HP;
    int hp   = bx - n * HP;
    int lane = threadIdx.x & 63;
    int wv   = threadIdx.x >> 6;          // 0..3
    int slot = blockIdx.y * 4 + wv;       // u32 slot 0..7 (32 channels each)
    int c0   = slot * 32;

    // destination wp for this lane: interior lanes 0..55 -> wp=lane+1;
    // lane 56 -> wp=0, lane 57 -> wp=57 (halo cols); 58..63 idle.
    int wp = (lane < WW) ? (lane + 1) : (lane == 56 ? 0 : (lane == 57 ? HP - 1 : -1));

    bool interior = (hp >= 1 && hp <= HH);
    u32 acc = 0;
    if (interior && lane < WW) {
        int h = hp - 1;
        const float* xr = x + (((size_t)n * CIN + c0) * HH + h) * WW + lane;
        #pragma unroll 16
        for (int c = 0; c < 32; ++c) {
            u64 b = __ballot(xr[(size_t)c * HWI] >= 0.0f);
            acc |= (u32)((b >> lane) & 1ull) << c;
        }
    }
    if (wp >= 0) {
        if (!(interior && lane < WW)) acc = 0;   // halo cells
        xb[(((size_t)n * HP + hp) * HP + wp) * 8 + slot] = acc;
    }
}

// ---------------- Pass 2: XNOR-popcount conv --------------------------------
// One thread = one output pixel; block handles CO_CHUNK consecutive co.
// Weights staged in LDS (9 KB/block), broadcast ds_read. a[72] u32 pinned in
// VGPRs across the co loop. co-loop unroll 2 interleaves two co's ds_reads
// and popcounts across the lgkmcnt boundary (round-6: VALUBusy 80%).
__global__ __launch_bounds__(256, 4) void conv_kernel(const u32* __restrict__ xb,
                                                      const u64* __restrict__ wb,
                                                      const u32* __restrict__ wcorr,
                                                      const float* __restrict__ alpha,
                                                      float* __restrict__ out) {
    __shared__ u32 w_lds[CO_CHUNK * 72];        // 9216 B

    int tid = threadIdx.x;
    int p   = blockIdx.x * 256 + tid;           // 0 .. 100351
    int c0  = blockIdx.y * CO_CHUNK;
    int n   = p / HWI;
    int rem = p - n * HWI;
    int h   = rem / WW;
    int w   = rem - h * WW;

    // ---- stage weights: 2304 u32 = 576 uint4; 256 threads: 256+256+64 ----
    const uint4* wsrc = (const uint4*)(wb + (size_t)c0 * 36);
    uint4* wdst = (uint4*)w_lds;
    uint4 s0 = wsrc[tid];
    uint4 s1 = wsrc[tid + 256];
    uint4 s2 = wsrc[512 + (tid & 63)];          // always in-bounds; stored if tid<64

    // ---- load 9 taps x 8 u32 of activations (32B/tap, 2x dwordx4) ----
    const u32* base = xb + (((size_t)n * HP + h) * HP + w) * 8;
    u32 a[72];
    #pragma unroll
    for (int t = 0; t < 9; ++t) {
        const uint4* tb = (const uint4*)(base + ((t / 3) * HP + (t % 3)) * 8);
        uint4 v0 = tb[0], v1 = tb[1];
        a[t*8+0]=v0.x; a[t*8+1]=v0.y; a[t*8+2]=v0.z; a[t*8+3]=v0.w;
        a[t*8+4]=v1.x; a[t*8+5]=v1.y; a[t*8+6]=v1.z; a[t*8+7]=v1.w;
    }

    wdst[tid]       = s0;
    wdst[tid + 256] = s1;
    if (tid < 64) wdst[512 + tid] = s2;
    __syncthreads();

    // Pin activation words in VGPRs; forbids load-sinking/remat into co loop.
    #pragma unroll
    for (int k = 0; k < 72; ++k) asm volatile("" : "+v"(a[k]));

    int hs = (h == 0) ? 0 : ((h == HH - 1) ? 2 : 1);
    int ws = (w == 0) ? 0 : ((w == WW - 1) ? 2 : 1);
    int pid = hs * 3 + ws;
    int nv  = ((hs == 1) ? 3 : 2) * ((ws == 1) ? 3 : 2);  // # valid taps
    float basesum = (float)(256 * nv);

    const u32* wcp = wcorr + pid * COUT + c0;   // per-co: dword load, imm offset
    const float* alp = alpha + c0;
    float* op = out + (size_t)n * COUT * HWI + (size_t)c0 * HWI + rem;

    #pragma unroll 2
    for (int co = 0; co < CO_CHUNK; ++co) {
        const u32* wq = &w_lds[co * 72];        // broadcast ds_read x18 (b128)
        u32 P0 = 0, P1 = 0, P2 = 0, P3 = 0;    // 4 chains: v_bcnt accum fusion
        #pragma unroll
        for (int k = 0; k < 72; k += 4) {
            P0 += __builtin_popcount(a[k]     ^ wq[k]);
            P1 += __builtin_popcount(a[k + 1] ^ wq[k + 1]);
            P2 += __builtin_popcount(a[k + 2] ^ wq[k + 2]);
            P3 += __builtin_popcount(a[k + 3] ^ wq[k + 3]);
        }
        u32 P = (P0 + P1) + (P2 + P3) - wcp[co];  // remove halo taps' popc(w)
        float s = basesum - 2.0f * (float)(int)P;
        __builtin_nontemporal_store(s * alp[co], &op[(size_t)co * HWI]);
    }
}

extern "C" void kernel_launch(void* const* d_in, const int* in_sizes, int n_in,
                              void* d_out, int out_size, void* d_ws, size_t ws_size,
                              hipStream_t stream) {
    const float* x     = (const float*)d_in[0];
    const float* M     = (const float*)d_in[1];
    const float* alpha = (const float*)d_in[2];
    float* out = (float*)d_out;

    char* ws = (char*)d_ws;
    u32* xb    = (u32*)ws;
    u64* wb    = (u64*)(ws + XB_BYTES);
    u32* wcorr = (u32*)(ws + XB_BYTES + WB_BYTES);

    pack_w_kernel<<<COUT, 256, 0, stream>>>(M, wb, wcorr);
    dim3 pgrid(NN * HP, 2);
    pack_x_kernel<<<pgrid, 256, 0, stream>>>(x, xb);   // writes halo: no memset
    dim3 cgrid((NN * HWI) / 256, COUT / CO_CHUNK);
    conv_kernel<<<cgrid, 256, 0, stream>>>(xb, wb, wcorr, alpha, out);
}